// Round 5
// baseline (175.713 us; speedup 1.0000x reference)
//
#include <hip/hip_runtime.h>
#include <hip/hip_bf16.h>
#include <math.h>

#define N_TOTAL 8192
#define D_DIM   256
#define INV_T   10.0f
#define NT 64                  // 8192/128; triangular grid
#define NBLOCKS (NT * (NT + 1) / 2)

typedef __bf16 bf16_8 __attribute__((ext_vector_type(8)));
typedef float  f32x4  __attribute__((ext_vector_type(4)));

__device__ __forceinline__ unsigned short f2bf(float f) {
    unsigned int u = __float_as_uint(f);
    return (unsigned short)((u + 0x7FFFu + ((u >> 16) & 1u)) >> 16);
}

// Kernel 1: L2-normalize concat(q,k) -> row-major bf16 F[8192][256] (fully coalesced);
// zero S / counter / possum.
__global__ __launch_bounds__(256) void normalize_kernel(
    const float* __restrict__ q, const float* __restrict__ k,
    unsigned short* __restrict__ F, float* __restrict__ S,
    int* __restrict__ counter, float* __restrict__ possum)
{
    if (threadIdx.x < 4) S[blockIdx.x * 4 + threadIdx.x] = 0.f;
    if (blockIdx.x == 0 && threadIdx.x == 0) { *counter = 0; *possum = 0.f; }
    int row  = blockIdx.x * 4 + (threadIdx.x >> 6);
    int lane = threadIdx.x & 63;
    const float* src = (row < 4096) ? (q + (size_t)row * D_DIM)
                                    : (k + (size_t)(row - 4096) * D_DIM);
    float4 v = ((const float4*)src)[lane];
    float ss = v.x*v.x + v.y*v.y + v.z*v.z + v.w*v.w;
    #pragma unroll
    for (int off = 32; off > 0; off >>= 1) ss += __shfl_xor(ss, off, 64);
    float inv = 1.0f / fmaxf(sqrtf(ss), 1e-12f);
    ushort4 o;
    o.x = f2bf(v.x * inv); o.y = f2bf(v.y * inv);
    o.z = f2bf(v.z * inv); o.w = f2bf(v.w * inv);
    ((ushort4*)(F + (size_t)row * D_DIM))[lane] = o;
}

__device__ __forceinline__ int tri_off(int x) { return x * NT - (x * (x - 1)) / 2; }

// Kernel 2: upper-triangular F*F^T, NO LDS staging, no main-loop barriers.
// Each wave computes a 64x64 tile; fragments loaded straight from global
// (16 rows x 64 B per instruction, fully-consumed sectors; F is L2-resident).
__global__ __launch_bounds__(256) void simloss_gemm(
    const unsigned short* __restrict__ F,
    float* __restrict__ S, int* __restrict__ counter,
    float* __restrict__ possum, float* __restrict__ out)
{
    __shared__ float fsum[4];
    __shared__ int   is_last;

    int b  = blockIdx.x;
    int bx = (int)(64.5f - sqrtf(64.5f * 64.5f - 2.0f * (float)b));
    if (bx < 0) bx = 0; if (bx > NT - 1) bx = NT - 1;
    while (bx > 0 && tri_off(bx) > b) --bx;
    while (bx < NT - 1 && tri_off(bx + 1) <= b) ++bx;
    const int by = bx + (b - tri_off(bx));
    const bool is_diag = (bx == by);

    const int i0 = bx * 128;
    const int j0 = by * 128;
    const int tid  = threadIdx.x;
    const int wave = tid >> 6;
    const int lane = tid & 63;
    const int wm = (wave & 1) * 64;   // waves 0&2 share A rows, 0&1 share B rows (L1 reuse)
    const int wn = (wave >> 1) * 64;
    const int g  = lane >> 4;
    const int cj = lane & 15;

    // per-lane fragment base: row (base + cj), k-offset g*8  [A: m=lane&15, k=quad*8+j]
    const unsigned short* Abase = F + (size_t)(i0 + wm + cj) * D_DIM + g * 8;
    const unsigned short* Bbase = F + (size_t)(j0 + wn + cj) * D_DIM + g * 8;

    f32x4 acc[4][4];
    #pragma unroll
    for (int a = 0; a < 4; ++a)
        #pragma unroll
        for (int c = 0; c < 4; ++c)
            acc[a][c] = (f32x4){0.f, 0.f, 0.f, 0.f};

    #pragma unroll
    for (int kc = 0; kc < 8; ++kc) {
        bf16_8 a[4], bb[4];
        #pragma unroll
        for (int t = 0; t < 4; ++t) {
            a[t]  = *(const bf16_8*)(Abase + t * 16 * D_DIM + kc * 32);
            bb[t] = *(const bf16_8*)(Bbase + t * 16 * D_DIM + kc * 32);
        }
        #pragma unroll
        for (int ti = 0; ti < 4; ++ti)
            #pragma unroll
            for (int tj = 0; tj < 4; ++tj)
                acc[ti][tj] = __builtin_amdgcn_mfma_f32_16x16x32_bf16(
                    a[ti], bb[tj], acc[ti][tj], 0, 0, 0);
    }

    // ---- epilogue. C/D layout: col = lane&15, row = (lane>>4)*4 + reg [m89/m91]
    // positive-pair tiles (by==bx+32): accumulate 2*INV_T*sim over the local diagonal
    if (by == bx + 32 && wm == wn) {
        float ds = 0.f;
        if ((cj >> 2) == g) {
            #pragma unroll
            for (int ti = 0; ti < 4; ++ti) ds += acc[ti][ti][cj & 3];
        }
        #pragma unroll
        for (int off = 1; off < 64; off <<= 1) ds += __shfl_xor(ds, off, 64);
        if (lane == 0) atomicAdd(possum, 2.0f * INV_T * ds);
    }
    // diag tiles: poison self-similarity so exp -> 0
    if (is_diag && wm == wn && (cj >> 2) == g) {
        #pragma unroll
        for (int ti = 0; ti < 4; ++ti) acc[ti][ti][cj & 3] = -1e30f;
    }

    float colsum[4] = {0.f, 0.f, 0.f, 0.f};
    #pragma unroll
    for (int ti = 0; ti < 4; ++ti) {
        #pragma unroll
        for (int r = 0; r < 4; ++r) {
            float es = 0.f;
            #pragma unroll
            for (int tj = 0; tj < 4; ++tj) {
                float e = __expf(acc[ti][tj][r] * INV_T);
                es += e;
                colsum[tj] += e;
            }
            #pragma unroll
            for (int off = 1; off < 16; off <<= 1)
                es += __shfl_xor(es, off, 64);
            if (cj == 0) atomicAdd(&S[i0 + wm + ti * 16 + g * 4 + r], es);
        }
    }
    if (!is_diag) {
        #pragma unroll
        for (int tj = 0; tj < 4; ++tj) {
            float cs = colsum[tj];
            cs += __shfl_xor(cs, 16, 64);
            cs += __shfl_xor(cs, 32, 64);
            if (g == 0) atomicAdd(&S[j0 + wn + tj * 16 + cj], cs);
        }
    }

    // ---- lock-free last-block finalize (all cross-block data via device-scope atomics)
    __syncthreads();
    if (tid == 0)
        is_last = (__hip_atomic_fetch_add(counter, 1, __ATOMIC_RELEASE,
                                          __HIP_MEMORY_SCOPE_AGENT) == NBLOCKS - 1);
    __syncthreads();
    if (is_last) {
        __threadfence();   // executed by exactly one block
        float a2 = 0.f;
        for (int i = tid; i < N_TOTAL; i += 256)
            a2 += __logf(__hip_atomic_load(&S[i], __ATOMIC_RELAXED,
                                           __HIP_MEMORY_SCOPE_AGENT));
        #pragma unroll
        for (int off = 32; off > 0; off >>= 1) a2 += __shfl_xor(a2, off, 64);
        if (lane == 0) fsum[wave] = a2;
        __syncthreads();
        if (tid == 0) {
            float ps = __hip_atomic_load(possum, __ATOMIC_RELAXED,
                                         __HIP_MEMORY_SCOPE_AGENT);
            out[0] = (fsum[0] + fsum[1] + fsum[2] + fsum[3] - ps) * (1.0f / N_TOTAL);
        }
    }
}

extern "C" void kernel_launch(void* const* d_in, const int* in_sizes, int n_in,
                              void* d_out, int out_size, void* d_ws, size_t ws_size,
                              hipStream_t stream) {
    const float* q = (const float*)d_in[0];
    const float* k = (const float*)d_in[1];
    float* out = (float*)d_out;

    char* ws = (char*)d_ws;
    const size_t f_bytes = (size_t)N_TOTAL * D_DIM * sizeof(unsigned short); // 4 MB
    unsigned short* F = (unsigned short*)ws;
    float* S      = (float*)(ws + f_bytes);
    int*   cnt    = (int*)(ws + f_bytes + N_TOTAL * sizeof(float));
    float* possum = (float*)(ws + f_bytes + N_TOTAL * sizeof(float) + 16);

    normalize_kernel<<<N_TOTAL / 4, 256, 0, stream>>>(q, k, F, S, cnt, possum);
    simloss_gemm<<<NBLOCKS, 256, 0, stream>>>(F, S, cnt, possum, out);
}

// Round 6
// 139.794 us; speedup vs baseline: 1.2569x; 1.2569x over previous
//
#include <hip/hip_runtime.h>
#include <hip/hip_bf16.h>
#include <math.h>

#define N_TOTAL 8192
#define D_DIM   256
#define INV_T   10.0f
#define BM 128
#define BK 32
#define LDS_STRIDE 40          // elements; 80 B rows. Reads: 2-way (free). Writes: free w/ swizzle.
#define NT 64                  // 8192/128; triangular grid
#define NBLOCKS (NT * (NT + 1) / 2)

typedef __bf16 bf16_8 __attribute__((ext_vector_type(8)));
typedef float  f32x4  __attribute__((ext_vector_type(4)));

__device__ __forceinline__ unsigned short f2bf(float f) {
    unsigned int u = __float_as_uint(f);
    return (unsigned short)((u + 0x7FFFu + ((u >> 16) & 1u)) >> 16);
}

// Kernel 1: L2-normalize concat(q,k) -> row-major bf16 F[8192][256]; zero S/counter/possum.
__global__ __launch_bounds__(256) void normalize_kernel(
    const float* __restrict__ q, const float* __restrict__ k,
    unsigned short* __restrict__ F, float* __restrict__ S,
    int* __restrict__ counter, float* __restrict__ possum)
{
    if (threadIdx.x < 4) S[blockIdx.x * 4 + threadIdx.x] = 0.f;
    if (blockIdx.x == 0 && threadIdx.x == 0) { *counter = 0; *possum = 0.f; }
    int row  = blockIdx.x * 4 + (threadIdx.x >> 6);
    int lane = threadIdx.x & 63;
    const float* src = (row < 4096) ? (q + (size_t)row * D_DIM)
                                    : (k + (size_t)(row - 4096) * D_DIM);
    float4 v = ((const float4*)src)[lane];
    float ss = v.x*v.x + v.y*v.y + v.z*v.z + v.w*v.w;
    #pragma unroll
    for (int off = 32; off > 0; off >>= 1) ss += __shfl_xor(ss, off, 64);
    float inv = 1.0f / fmaxf(sqrtf(ss), 1e-12f);
    ushort4 o;
    o.x = f2bf(v.x * inv); o.y = f2bf(v.y * inv);
    o.z = f2bf(v.z * inv); o.w = f2bf(v.w * inv);
    ((ushort4*)(F + (size_t)row * D_DIM))[lane] = o;
}

__device__ __forceinline__ int tri_off(int x) { return x * NT - (x * (x - 1)) / 2; }

// Kernel 2: upper-triangular tiled F*F^T (R1 VGPR-staged structure), fused exp
// epilogue + lock-free last-block finalize.
__global__ __launch_bounds__(256) void simloss_gemm(
    const __hip_bfloat16* __restrict__ F,
    float* __restrict__ S, int* __restrict__ counter,
    float* __restrict__ possum, float* __restrict__ out)
{
    __shared__ __hip_bfloat16 As[BM * LDS_STRIDE];  // 10 KB
    __shared__ __hip_bfloat16 Bs[BM * LDS_STRIDE];  // 10 KB
    __shared__ float fsum[4];
    __shared__ int   is_last;

    int b  = blockIdx.x;
    int bx = (int)(64.5f - sqrtf(64.5f * 64.5f - 2.0f * (float)b));
    if (bx < 0) bx = 0; if (bx > NT - 1) bx = NT - 1;
    while (bx > 0 && tri_off(bx) > b) --bx;
    while (bx < NT - 1 && tri_off(bx + 1) <= b) ++bx;
    const int by = bx + (b - tri_off(bx));
    const bool is_diag = (bx == by);

    const int i0 = bx * BM;
    const int j0 = by * BM;
    const int tid  = threadIdx.x;
    const int wave = tid >> 6;
    const int lane = tid & 63;
    const int wm = (wave & 1) * 64;
    const int wn = (wave >> 1) * 64;
    const int g  = lane >> 4;
    const int cj = lane & 15;

    f32x4 acc[4][4];
    #pragma unroll
    for (int a = 0; a < 4; ++a)
        #pragma unroll
        for (int c = 0; c < 4; ++c)
            acc[a][c] = (f32x4){0.f, 0.f, 0.f, 0.f};

    // staging map: idx -> (row, chunk) such that each 16-lane phase writes
    // rows {r0,r0+2,r0+4,r0+6} x chunks{0..3}: bank offsets r*20 mod 32 =
    // {0,8,16,24} -> every bank exactly 2x -> conflict-free ds_write_b128.
    int s_r[2], s_ck[2];
    #pragma unroll
    for (int c = 0; c < 2; ++c) {
        int idx = tid + c * 256;           // 0..511
        int p   = idx >> 4;                // 16-lane phase id
        int bq  = idx & 15;
        s_r[c]  = (p >> 1) * 8 + (bq >> 2) * 2 + (p & 1);
        s_ck[c] = bq & 3;
    }

    for (int kk = 0; kk < D_DIM; kk += BK) {
        #pragma unroll
        for (int c = 0; c < 2; ++c) {
            const int r = s_r[c], ck = s_ck[c];
            uint4 av = *(const uint4*)(F + (size_t)(i0 + r) * D_DIM + kk + ck * 8);
            *(uint4*)(&As[r * LDS_STRIDE + ck * 8]) = av;
            uint4 bv = *(const uint4*)(F + (size_t)(j0 + r) * D_DIM + kk + ck * 8);
            *(uint4*)(&Bs[r * LDS_STRIDE + ck * 8]) = bv;
        }
        __syncthreads();

        bf16_8 a[4], bb[4];
        #pragma unroll
        for (int t = 0; t < 4; ++t) {
            a[t]  = *(const bf16_8*)(&As[(wm + t * 16 + cj) * LDS_STRIDE + g * 8]);
            bb[t] = *(const bf16_8*)(&Bs[(wn + t * 16 + cj) * LDS_STRIDE + g * 8]);
        }
        #pragma unroll
        for (int ti = 0; ti < 4; ++ti)
            #pragma unroll
            for (int tj = 0; tj < 4; ++tj)
                acc[ti][tj] = __builtin_amdgcn_mfma_f32_16x16x32_bf16(
                    a[ti], bb[tj], acc[ti][tj], 0, 0, 0);
        __syncthreads();
    }

    // ---- epilogue. C/D layout: col = lane&15, row = (lane>>4)*4 + reg [m89/m91]
    // positive-pair tiles (by==bx+32): accumulate 2*INV_T*sim over the local diagonal
    if (by == bx + 32 && wm == wn) {
        float ds = 0.f;
        if ((cj >> 2) == g) {
            #pragma unroll
            for (int ti = 0; ti < 4; ++ti) ds += acc[ti][ti][cj & 3];
        }
        #pragma unroll
        for (int off = 1; off < 64; off <<= 1) ds += __shfl_xor(ds, off, 64);
        if (lane == 0) atomicAdd(possum, 2.0f * INV_T * ds);
    }
    // diag tiles: poison self-similarity so exp -> 0
    if (is_diag && wm == wn && (cj >> 2) == g) {
        #pragma unroll
        for (int ti = 0; ti < 4; ++ti) acc[ti][ti][cj & 3] = -1e30f;
    }

    float colsum[4] = {0.f, 0.f, 0.f, 0.f};
    #pragma unroll
    for (int ti = 0; ti < 4; ++ti) {
        #pragma unroll
        for (int r = 0; r < 4; ++r) {
            float es = 0.f;
            #pragma unroll
            for (int tj = 0; tj < 4; ++tj) {
                float e = __expf(acc[ti][tj][r] * INV_T);
                es += e;
                colsum[tj] += e;
            }
            #pragma unroll
            for (int off = 1; off < 16; off <<= 1)
                es += __shfl_xor(es, off, 64);
            if (cj == 0) atomicAdd(&S[i0 + wm + ti * 16 + g * 4 + r], es);
        }
    }
    if (!is_diag) {
        #pragma unroll
        for (int tj = 0; tj < 4; ++tj) {
            float cs = colsum[tj];
            cs += __shfl_xor(cs, 16, 64);
            cs += __shfl_xor(cs, 32, 64);
            if (g == 0) atomicAdd(&S[j0 + wn + tj * 16 + cj], cs);
        }
    }

    // ---- lock-free last-block finalize (all cross-block data via device-scope atomics)
    __syncthreads();
    if (tid == 0)
        is_last = (__hip_atomic_fetch_add(counter, 1, __ATOMIC_RELEASE,
                                          __HIP_MEMORY_SCOPE_AGENT) == NBLOCKS - 1);
    __syncthreads();
    if (is_last) {
        __threadfence();   // executed by exactly one block
        float a2 = 0.f;
        for (int i = tid; i < N_TOTAL; i += 256)
            a2 += __logf(__hip_atomic_load(&S[i], __ATOMIC_RELAXED,
                                           __HIP_MEMORY_SCOPE_AGENT));
        #pragma unroll
        for (int off = 32; off > 0; off >>= 1) a2 += __shfl_xor(a2, off, 64);
        if (lane == 0) fsum[wave] = a2;
        __syncthreads();
        if (tid == 0) {
            float ps = __hip_atomic_load(possum, __ATOMIC_RELAXED,
                                         __HIP_MEMORY_SCOPE_AGENT);
            out[0] = (fsum[0] + fsum[1] + fsum[2] + fsum[3] - ps) * (1.0f / N_TOTAL);
        }
    }
}

extern "C" void kernel_launch(void* const* d_in, const int* in_sizes, int n_in,
                              void* d_out, int out_size, void* d_ws, size_t ws_size,
                              hipStream_t stream) {
    const float* q = (const float*)d_in[0];
    const float* k = (const float*)d_in[1];
    float* out = (float*)d_out;

    char* ws = (char*)d_ws;
    const size_t f_bytes = (size_t)N_TOTAL * D_DIM * sizeof(unsigned short); // 4 MB
    unsigned short* F = (unsigned short*)ws;
    float* S      = (float*)(ws + f_bytes);
    int*   cnt    = (int*)(ws + f_bytes + N_TOTAL * sizeof(float));
    float* possum = (float*)(ws + f_bytes + N_TOTAL * sizeof(float) + 16);

    normalize_kernel<<<N_TOTAL / 4, 256, 0, stream>>>(q, k, F, S, cnt, possum);
    simloss_gemm<<<NBLOCKS, 256, 0, stream>>>((const __hip_bfloat16*)F, S, cnt, possum, out);
}

// Round 7
// 132.802 us; speedup vs baseline: 1.3231x; 1.0527x over previous
//
#include <hip/hip_runtime.h>
#include <hip/hip_bf16.h>
#include <math.h>

#define N_TOTAL 8192
#define D_DIM   256
#define INV_T   10.0f
#define NCHUNK  32             // 32 chunks of 8 bf16 (16 B) per row
#define NT 64                  // 8192/128; triangular grid
#define NBLOCKS (NT * (NT + 1) / 2)

typedef __bf16 bf16_8 __attribute__((ext_vector_type(8)));
typedef float  f32x4  __attribute__((ext_vector_type(4)));

__device__ __forceinline__ unsigned short f2bf(float f) {
    unsigned int u = __float_as_uint(f);
    return (unsigned short)((u + 0x7FFFu + ((u >> 16) & 1u)) >> 16);
}

// Kernel 1: L2-normalize concat(q,k) -> Fs chunk-major: Fs[(c*8192+row)*8 .. +8)
// = bf16 elems 8c..8c+7 of row. Half-wave per row. Zero S/counter/possum.
__global__ __launch_bounds__(256) void normalize_stage(
    const float* __restrict__ q, const float* __restrict__ k,
    unsigned short* __restrict__ Fs, float* __restrict__ S,
    int* __restrict__ counter, float* __restrict__ possum)
{
    const int tid = threadIdx.x;
    if (tid < 8) S[blockIdx.x * 8 + tid] = 0.f;
    if (blockIdx.x == 0 && tid == 0) { *counter = 0; *possum = 0.f; }

    const int wave = tid >> 6, lane = tid & 63;
    const int h = lane >> 5, c = lane & 31;
    const int row = blockIdx.x * 8 + wave * 2 + h;
    const float* src = (row < 4096) ? q + (size_t)row * D_DIM
                                    : k + (size_t)(row - 4096) * D_DIM;
    float4 v0 = *(const float4*)(src + c * 8);
    float4 v1 = *(const float4*)(src + c * 8 + 4);
    float ss = v0.x*v0.x + v0.y*v0.y + v0.z*v0.z + v0.w*v0.w
             + v1.x*v1.x + v1.y*v1.y + v1.z*v1.z + v1.w*v1.w;
    #pragma unroll
    for (int off = 16; off > 0; off >>= 1) ss += __shfl_xor(ss, off, 64);  // 32-lane reduce
    float inv = 1.0f / fmaxf(sqrtf(ss), 1e-12f);
    uint4 o;
    o.x = f2bf(v0.x*inv) | ((unsigned)f2bf(v0.y*inv) << 16);
    o.y = f2bf(v0.z*inv) | ((unsigned)f2bf(v0.w*inv) << 16);
    o.z = f2bf(v1.x*inv) | ((unsigned)f2bf(v1.y*inv) << 16);
    o.w = f2bf(v1.z*inv) | ((unsigned)f2bf(v1.w*inv) << 16);
    *(uint4*)(Fs + ((size_t)c * N_TOTAL + row) * 8) = o;
}

__device__ __forceinline__ int tri_off(int x) { return x * NT - (x * (x - 1)) / 2; }

// Kernel 2: upper-triangular F*F^T. Chunk-major LDS (0-conflict b128 phases),
// VGPR-mediated staging with explicit next-iter prefetch in flight across the
// barrier. Fused exp epilogue + lock-free last-block finalize.
__global__ __launch_bounds__(256) void simloss_gemm(
    const unsigned short* __restrict__ Fs,
    float* __restrict__ S, int* __restrict__ counter,
    float* __restrict__ possum, float* __restrict__ out)
{
    __shared__ unsigned short As[128 * 32];   // 8 KB, 16B unit index = ck*128 + row
    __shared__ unsigned short Bs[128 * 32];   // 8 KB
    __shared__ float fsum[4];
    __shared__ int   is_last;

    int b  = blockIdx.x;
    int bx = (int)(64.5f - sqrtf(64.5f * 64.5f - 2.0f * (float)b));
    if (bx < 0) bx = 0; if (bx > NT - 1) bx = NT - 1;
    while (bx > 0 && tri_off(bx) > b) --bx;
    while (bx < NT - 1 && tri_off(bx + 1) <= b) ++bx;
    const int by = bx + (b - tri_off(bx));
    const bool is_diag = (bx == by);

    const int i0 = bx * 128;
    const int j0 = by * 128;
    const int tid  = threadIdx.x;
    const int wave = tid >> 6;
    const int lane = tid & 63;
    const int wm = (wave & 1) * 64;
    const int wn = (wave >> 1) * 64;
    const int g  = lane >> 4;
    const int cj = lane & 15;

    // staging map: u in {tid, tid+256} -> chunk-slot ck = u>>7, row = u&127.
    // Global: consecutive lanes read consecutive rows of one chunk (contiguous 1KB/wave).
    // LDS: ds_write_b128 to unit ck*128+row — contiguous 256B per 16-lane phase -> 0 conflicts.
    const int ck0 = tid >> 7,        r0 = tid & 127;
    const int ck1 = (tid + 256) >> 7, r1 = tid & 127;   // ck1 = ck0+2, r1 = r0

    f32x4 acc[4][4];
    #pragma unroll
    for (int a = 0; a < 4; ++a)
        #pragma unroll
        for (int c = 0; c < 4; ++c)
            acc[a][c] = (f32x4){0.f, 0.f, 0.f, 0.f};

    // prefetch k-chunk group 0
    uint4 av0 = *(const uint4*)(Fs + ((size_t)ck0 * N_TOTAL + i0 + r0) * 8);
    uint4 av1 = *(const uint4*)(Fs + ((size_t)ck1 * N_TOTAL + i0 + r1) * 8);
    uint4 bv0 = *(const uint4*)(Fs + ((size_t)ck0 * N_TOTAL + j0 + r0) * 8);
    uint4 bv1 = *(const uint4*)(Fs + ((size_t)ck1 * N_TOTAL + j0 + r1) * 8);

    #pragma unroll
    for (int kc = 0; kc < 8; ++kc) {
        if (kc) __syncthreads();             // previous iteration's ds_reads done
        *(uint4*)(&As[((size_t)ck0 * 128 + r0) * 8]) = av0;
        *(uint4*)(&As[((size_t)ck1 * 128 + r1) * 8]) = av1;
        *(uint4*)(&Bs[((size_t)ck0 * 128 + r0) * 8]) = bv0;
        *(uint4*)(&Bs[((size_t)ck1 * 128 + r1) * 8]) = bv1;
        if (kc < 7) {                        // issue next-iter loads; in flight across barrier
            const size_t kb = (size_t)(kc + 1) * 4 * N_TOTAL;
            av0 = *(const uint4*)(Fs + (kb + (size_t)ck0 * N_TOTAL + i0 + r0) * 8);
            av1 = *(const uint4*)(Fs + (kb + (size_t)ck1 * N_TOTAL + i0 + r1) * 8);
            bv0 = *(const uint4*)(Fs + (kb + (size_t)ck0 * N_TOTAL + j0 + r0) * 8);
            bv1 = *(const uint4*)(Fs + (kb + (size_t)ck1 * N_TOTAL + j0 + r1) * 8);
        }
        __syncthreads();                     // staged tile visible

        bf16_8 a[4], bb[4];
        #pragma unroll
        for (int t = 0; t < 4; ++t) {
            a[t]  = *(const bf16_8*)(&As[((size_t)g * 128 + wm + t * 16 + cj) * 8]);
            bb[t] = *(const bf16_8*)(&Bs[((size_t)g * 128 + wn + t * 16 + cj) * 8]);
        }
        #pragma unroll
        for (int ti = 0; ti < 4; ++ti)
            #pragma unroll
            for (int tj = 0; tj < 4; ++tj)
                acc[ti][tj] = __builtin_amdgcn_mfma_f32_16x16x32_bf16(
                    a[ti], bb[tj], acc[ti][tj], 0, 0, 0);
    }

    // ---- epilogue. C/D layout: col = lane&15, row = (lane>>4)*4 + reg [m89/m91]
    if (by == bx + 32 && wm == wn) {
        float ds = 0.f;
        if ((cj >> 2) == g) {
            #pragma unroll
            for (int ti = 0; ti < 4; ++ti) ds += acc[ti][ti][cj & 3];
        }
        #pragma unroll
        for (int off = 1; off < 64; off <<= 1) ds += __shfl_xor(ds, off, 64);
        if (lane == 0) atomicAdd(possum, 2.0f * INV_T * ds);
    }
    if (is_diag && wm == wn && (cj >> 2) == g) {
        #pragma unroll
        for (int ti = 0; ti < 4; ++ti) acc[ti][ti][cj & 3] = -1e30f;
    }

    float colsum[4] = {0.f, 0.f, 0.f, 0.f};
    #pragma unroll
    for (int ti = 0; ti < 4; ++ti) {
        #pragma unroll
        for (int r = 0; r < 4; ++r) {
            float es = 0.f;
            #pragma unroll
            for (int tj = 0; tj < 4; ++tj) {
                float e = __expf(acc[ti][tj][r] * INV_T);
                es += e;
                colsum[tj] += e;
            }
            #pragma unroll
            for (int off = 1; off < 16; off <<= 1)
                es += __shfl_xor(es, off, 64);
            if (cj == 0) atomicAdd(&S[i0 + wm + ti * 16 + g * 4 + r], es);
        }
    }
    if (!is_diag) {
        #pragma unroll
        for (int tj = 0; tj < 4; ++tj) {
            float cs = colsum[tj];
            cs += __shfl_xor(cs, 16, 64);
            cs += __shfl_xor(cs, 32, 64);
            if (g == 0) atomicAdd(&S[j0 + wn + tj * 16 + cj], cs);
        }
    }

    // ---- lock-free last-block finalize
    __syncthreads();
    if (tid == 0)
        is_last = (__hip_atomic_fetch_add(counter, 1, __ATOMIC_RELEASE,
                                          __HIP_MEMORY_SCOPE_AGENT) == NBLOCKS - 1);
    __syncthreads();
    if (is_last) {
        __threadfence();   // executed by exactly one block
        float a2 = 0.f;
        for (int i = tid; i < N_TOTAL; i += 256)
            a2 += __logf(__hip_atomic_load(&S[i], __ATOMIC_RELAXED,
                                           __HIP_MEMORY_SCOPE_AGENT));
        #pragma unroll
        for (int off = 32; off > 0; off >>= 1) a2 += __shfl_xor(a2, off, 64);
        if (lane == 0) fsum[wave] = a2;
        __syncthreads();
        if (tid == 0) {
            float ps = __hip_atomic_load(possum, __ATOMIC_RELAXED,
                                         __HIP_MEMORY_SCOPE_AGENT);
            out[0] = (fsum[0] + fsum[1] + fsum[2] + fsum[3] - ps) * (1.0f / N_TOTAL);
        }
    }
}

extern "C" void kernel_launch(void* const* d_in, const int* in_sizes, int n_in,
                              void* d_out, int out_size, void* d_ws, size_t ws_size,
                              hipStream_t stream) {
    const float* q = (const float*)d_in[0];
    const float* k = (const float*)d_in[1];
    float* out = (float*)d_out;

    char* ws = (char*)d_ws;
    const size_t f_bytes = (size_t)N_TOTAL * D_DIM * sizeof(unsigned short); // 4 MB
    unsigned short* Fs = (unsigned short*)ws;
    float* S      = (float*)(ws + f_bytes);
    int*   cnt    = (int*)(ws + f_bytes + N_TOTAL * sizeof(float));
    float* possum = (float*)(ws + f_bytes + N_TOTAL * sizeof(float) + 16);

    normalize_stage<<<N_TOTAL / 8, 256, 0, stream>>>(q, k, Fs, S, cnt, possum);
    simloss_gemm<<<NBLOCKS, 256, 0, stream>>>(Fs, S, cnt, possum, out);
}